// Round 1
// baseline (938.145 us; speedup 1.0000x reference)
//
#include <hip/hip_runtime.h>

typedef unsigned short ushort_t;
typedef __attribute__((ext_vector_type(8))) __bf16 bf8v;
typedef __attribute__((ext_vector_type(4))) float f4v;
typedef __attribute__((ext_vector_type(4))) unsigned short us4v;

#define MFMA(a, b, c) __builtin_amdgcn_mfma_f32_16x16x32_bf16((a), (b), (c), 0, 0, 0)

#define B_TOT 8192
#define T_STEPS 16
#define M_TILE 32
#define LDH 264      // 256 + 8 pad (16B-aligned rows, bank-spread)
#define LDS_SM 72    // 64 + 8 pad
#define LDMID 168    // 160 + 8 pad

// bf16 weight workspace offsets (ushort units)
#define OW1I 0
#define OW1H 16384
#define OWF1 81920
#define OW1O 98304
#define OW2I 114688
#define OW2H 131072
#define OWF2 196608
#define OW2O 212992
#define OW3I 229376   // [256][160] permuted: 0-63=out1 cols, 64-127=out2 cols, 128-129=cue, 130-159=0
#define OW3H 270336
#define OW3O 335872
#define OWFC 352256   // [16][64], rows 2..15 zero
#define WS_TOTAL 353280

// output offsets (float units), concatenated in reference return order
#define O_OSEQ 0
#define O_H1   262144
#define O_H2   2359296
#define O_H3   4456448
#define O_H4   6553600
#define O_O1   7077888
#define O_O2   15466496
#define O_CUE  23855104
#define O_F1   24117248
#define O_F2   57671680
#define O_OFA  91226112

__device__ __forceinline__ ushort_t f2bf(float f) {
  union { float f; unsigned u; } v; v.f = f;
  unsigned r = v.u + 0x7fffu + ((v.u >> 16) & 1u);  // round-to-nearest-even
  return (ushort_t)(r >> 16);
}

__device__ __forceinline__ float fast_tanh(float x) {
  // tanh(x) = 1 - 2/(e^{2x}+1); exact at +/-inf, ~1e-6 abs err
  float e = __expf(2.0f * x);
  return 1.0f - 2.0f * __builtin_amdgcn_rcpf(e + 1.0f);
}

__device__ __forceinline__ void store_bf4(ushort_t* p, f4v v) {
  us4v q;
  q[0] = f2bf(v[0]); q[1] = f2bf(v[1]); q[2] = f2bf(v[2]); q[3] = f2bf(v[3]);
  *(us4v*)p = q;
}

__global__ void prep_kernel(const float* __restrict__ W1i, const float* __restrict__ W1h,
                            const float* __restrict__ Wf1, const float* __restrict__ W1o,
                            const float* __restrict__ W2i, const float* __restrict__ W2h,
                            const float* __restrict__ Wf2, const float* __restrict__ W2o,
                            const float* __restrict__ W3i, const float* __restrict__ W3h,
                            const float* __restrict__ W3o, const float* __restrict__ Wfc,
                            ushort_t* __restrict__ ws) {
  int i = blockIdx.x * blockDim.x + threadIdx.x;
  if (i >= WS_TOTAL) return;
  float v;
  if (i < OW1H)       v = W1i[i - OW1I];
  else if (i < OWF1)  v = W1h[i - OW1H];
  else if (i < OW1O)  v = Wf1[i - OWF1];
  else if (i < OW2I)  v = W1o[i - OW1O];
  else if (i < OW2H)  v = W2i[i - OW2I];
  else if (i < OWF2)  v = W2h[i - OW2H];
  else if (i < OW2O)  v = Wf2[i - OWF2];
  else if (i < OW3I)  v = W2o[i - OW2O];
  else if (i < OW3H) {
    int idx = i - OW3I; int j = idx / 160; int k = idx - j * 160;
    if (k < 64)       v = W3i[j * 130 + 2 + k];
    else if (k < 128) v = W3i[j * 130 + 66 + (k - 64)];
    else if (k < 130) v = W3i[j * 130 + (k - 128)];
    else              v = 0.0f;
  }
  else if (i < OW3O)  v = W3h[i - OW3H];
  else if (i < OWFC)  v = W3o[i - OW3O];
  else {
    int idx = i - OWFC; int j = idx / 64; int k = idx - j * 64;
    v = (j < 2) ? Wfc[j * 64 + k] : 0.0f;
  }
  ws[i] = f2bf(v);
}

__launch_bounds__(512)
__global__ void rnn_kernel(const float* __restrict__ x, const float* __restrict__ cue,
                           const float* __restrict__ hc1, const float* __restrict__ hc2,
                           const float* __restrict__ hc3, const float* __restrict__ hc4,
                           const float* __restrict__ b1i, const float* __restrict__ b1h,
                           const float* __restrict__ bf1p, const float* __restrict__ b1o,
                           const float* __restrict__ b2i, const float* __restrict__ b2h,
                           const float* __restrict__ bf2p, const float* __restrict__ b2o,
                           const float* __restrict__ b3i, const float* __restrict__ b3h,
                           const float* __restrict__ b3o, const float* __restrict__ bfc,
                           const ushort_t* __restrict__ ws, float* __restrict__ out) {
  __shared__ ushort_t hs1[M_TILE * LDH], hs2[M_TILE * LDH], hs3[M_TILE * LDH];
  __shared__ ushort_t h4s[M_TILE * LDS_SM], xs[M_TILE * LDS_SM], ofs[M_TILE * LDS_SM];
  __shared__ ushort_t mid[M_TILE * LDMID];

  const int tid  = threadIdx.x;
  const int m0   = blockIdx.x * M_TILE;
  const int lane = tid & 63;
  const int w    = tid >> 6;       // wave 0..7
  const int ln   = lane & 15;
  const int quad = lane >> 4;
  const int koff = quad * 8;
  const int jt0  = 2 * w;          // first j-tile for 256-wide GEMMs

  // ---------------- init: states -> LDS (bf16) ----------------
  for (int i = tid; i < M_TILE * 256; i += 512) {
    int m = i >> 8, j = i & 255;
    hs1[m * LDH + j] = f2bf(hc1[(m0 + m) * 256 + j]);
    hs2[m * LDH + j] = f2bf(hc2[(m0 + m) * 256 + j]);
    hs3[m * LDH + j] = f2bf(hc3[(m0 + m) * 256 + j]);
  }
  for (int i = tid; i < M_TILE * 64; i += 512) {
    int m = i >> 6, j = i & 63;
    h4s[m * LDS_SM + j] = f2bf(hc4[(m0 + m) * 64 + j]);
  }
  for (int i = tid; i < M_TILE * LDMID; i += 512) mid[i] = 0;
  {
    // cue_arr output: 512 threads = 16 t x 32 rows
    int t = tid >> 5, r = tid & 31;
    float c = cue[m0 + r];
    float* oc = out + O_CUE + ((size_t)t * B_TOT + m0 + r) * 2;
    oc[0] = c * 10.0f;
    oc[1] = 10.0f * fabsf(c - 1.0f);
  }
  __syncthreads();
  if (tid < M_TILE) {
    float c = cue[m0 + tid];
    mid[tid * LDMID + 128] = f2bf(c * 10.0f);
    mid[tid * LDMID + 129] = f2bf(10.0f * fabsf(c - 1.0f));
  }

  // ---------------- per-thread bias registers (t-invariant) ----------------
  f4v bf1v[2], bf2v[2], bih1v[2], bih2v[2], b3shv[2];
#pragma unroll
  for (int i = 0; i < 2; ++i) {
    int j0 = (jt0 + i) * 16 + quad * 4;
#pragma unroll
    for (int r = 0; r < 4; ++r) {
      bf1v[i][r]  = bf1p[j0 + r];
      bf2v[i][r]  = bf2p[j0 + r];
      bih1v[i][r] = b1i[j0 + r] + b1h[j0 + r];
      bih2v[i][r] = b2i[j0 + r] + b2h[j0 + r];
      b3shv[i][r] = b3i[j0 + r] + b3h[j0 + r];
    }
  }
  // S3 (out1/out2): waves 0-3 -> out1 (stack1), waves 4-7 -> out2 (stack2)
  const int jto3 = w & 3;
  const int j0o3 = jto3 * 16 + quad * 4;
  const bool isOut2 = (w >= 4);
  f4v bo3v;
#pragma unroll
  for (int r = 0; r < 4; ++r) bo3v[r] = isOut2 ? b2o[j0o3 + r] : b1o[j0o3 + r];
  // S5 (o GEMM): jto5 = w>>1, mto5 = w&1
  const int jto5 = w >> 1;
  const int j0o5 = jto5 * 16 + quad * 4;
  const int mo5  = (w & 1) * 16 + ln;
  f4v b3ov;
#pragma unroll
  for (int r = 0; r < 4; ++r) b3ov[r] = b3o[j0o5 + r];
  const float bfcv0 = bfc[0], bfcv1 = bfc[1];

  __syncthreads();

  f4v acc1[2][2], acc2[2][2], acc3[2][2];

  for (int t = 0; t < T_STEPS; ++t) {
    // ======== S0: stage x[t] tile -> xs ; feed1/feed2 GEMMs (read h4s) ========
    {
      int r = tid >> 4, c4 = (tid & 15) * 4;
      const float* xp = x + ((size_t)t * B_TOT + m0 + r) * 64 + c4;
      f4v xv = *(const f4v*)xp;
      store_bf4(&xs[r * LDS_SM + c4], xv);
    }
    {
      f4v aF1[2][2], aF2[2][2];
#pragma unroll
      for (int i = 0; i < 2; ++i) {
#pragma unroll
        for (int mt = 0; mt < 2; ++mt) { aF1[i][mt] = bf1v[i]; aF2[i][mt] = bf2v[i]; }
      }
#pragma unroll
      for (int kk = 0; kk < 64; kk += 32) {
        bf8v b0 = *(const bf8v*)&h4s[ln * LDS_SM + kk + koff];
        bf8v b1 = *(const bf8v*)&h4s[(16 + ln) * LDS_SM + kk + koff];
#pragma unroll
        for (int i = 0; i < 2; ++i) {
          const int ar = ((jt0 + i) * 16 + ln) * 64 + kk + koff;
          bf8v a1 = *(const bf8v*)&ws[OWF1 + ar];
          bf8v a2 = *(const bf8v*)&ws[OWF2 + ar];
          aF1[i][0] = MFMA(a1, b0, aF1[i][0]);
          aF1[i][1] = MFMA(a1, b1, aF1[i][1]);
          aF2[i][0] = MFMA(a2, b0, aF2[i][0]);
          aF2[i][1] = MFMA(a2, b1, aF2[i][1]);
        }
      }
      // epilogue: write f1/f2 (pre-tanh), seed acc1/acc2 with tanh(feed)+bias, seed acc3 with bias
#pragma unroll
      for (int i = 0; i < 2; ++i) {
#pragma unroll
        for (int mt = 0; mt < 2; ++mt) {
          int j0 = (jt0 + i) * 16 + quad * 4;
          int m  = mt * 16 + ln;
          size_t rowoff = ((size_t)t * B_TOT + m0 + m) * 256 + j0;
          *(f4v*)(out + O_F1 + rowoff) = aF1[i][mt];
          *(f4v*)(out + O_F2 + rowoff) = aF2[i][mt];
          f4v t1, t2;
#pragma unroll
          for (int r = 0; r < 4; ++r) {
            t1[r] = fast_tanh(aF1[i][mt][r]) + bih1v[i][r];
            t2[r] = fast_tanh(aF2[i][mt][r]) + bih2v[i][r];
          }
          acc1[i][mt] = t1; acc2[i][mt] = t2; acc3[i][mt] = b3shv[i];
        }
      }
    }
    __syncthreads();  // SYNC1: xs ready

    // ======== S1: h1n/h2n GEMMs (ih from xs, hh from hs1/hs2) + hh3 into acc3 ========
#pragma unroll
    for (int kk = 0; kk < 64; kk += 32) {
      bf8v b0 = *(const bf8v*)&xs[ln * LDS_SM + kk + koff];
      bf8v b1 = *(const bf8v*)&xs[(16 + ln) * LDS_SM + kk + koff];
#pragma unroll
      for (int i = 0; i < 2; ++i) {
        const int ar = ((jt0 + i) * 16 + ln) * 64 + kk + koff;
        bf8v a1 = *(const bf8v*)&ws[OW1I + ar];
        bf8v a2 = *(const bf8v*)&ws[OW2I + ar];
        acc1[i][0] = MFMA(a1, b0, acc1[i][0]);
        acc1[i][1] = MFMA(a1, b1, acc1[i][1]);
        acc2[i][0] = MFMA(a2, b0, acc2[i][0]);
        acc2[i][1] = MFMA(a2, b1, acc2[i][1]);
      }
    }
#pragma unroll
    for (int kk = 0; kk < 256; kk += 32) {
      bf8v q1a = *(const bf8v*)&hs1[ln * LDH + kk + koff];
      bf8v q1b = *(const bf8v*)&hs1[(16 + ln) * LDH + kk + koff];
      bf8v q2a = *(const bf8v*)&hs2[ln * LDH + kk + koff];
      bf8v q2b = *(const bf8v*)&hs2[(16 + ln) * LDH + kk + koff];
      bf8v q3a = *(const bf8v*)&hs3[ln * LDH + kk + koff];
      bf8v q3b = *(const bf8v*)&hs3[(16 + ln) * LDH + kk + koff];
#pragma unroll
      for (int i = 0; i < 2; ++i) {
        const int ar = ((jt0 + i) * 16 + ln) * 256 + kk + koff;
        bf8v a1 = *(const bf8v*)&ws[OW1H + ar];
        bf8v a2 = *(const bf8v*)&ws[OW2H + ar];
        bf8v a3 = *(const bf8v*)&ws[OW3H + ar];
        acc1[i][0] = MFMA(a1, q1a, acc1[i][0]);
        acc1[i][1] = MFMA(a1, q1b, acc1[i][1]);
        acc2[i][0] = MFMA(a2, q2a, acc2[i][0]);
        acc2[i][1] = MFMA(a2, q2b, acc2[i][1]);
        acc3[i][0] = MFMA(a3, q3a, acc3[i][0]);
        acc3[i][1] = MFMA(a3, q3b, acc3[i][1]);
      }
    }
#pragma unroll
    for (int i = 0; i < 2; ++i) {
#pragma unroll
      for (int mt = 0; mt < 2; ++mt) {
#pragma unroll
        for (int r = 0; r < 4; ++r) {
          acc1[i][mt][r] = fast_tanh(acc1[i][mt][r]);
          acc2[i][mt][r] = fast_tanh(acc2[i][mt][r]);
        }
      }
    }
    if (t == T_STEPS - 1) {
#pragma unroll
      for (int i = 0; i < 2; ++i) {
#pragma unroll
        for (int mt = 0; mt < 2; ++mt) {
          int j0 = (jt0 + i) * 16 + quad * 4;
          int m  = mt * 16 + ln;
          *(f4v*)(out + O_H1 + (size_t)(m0 + m) * 256 + j0) = acc1[i][mt];
          *(f4v*)(out + O_H2 + (size_t)(m0 + m) * 256 + j0) = acc2[i][mt];
        }
      }
    }
    __syncthreads();  // SYNC2: all reads of old hs1/hs2/hs3 done

    // ======== S2: write back new h1/h2 states ========
#pragma unroll
    for (int i = 0; i < 2; ++i) {
#pragma unroll
      for (int mt = 0; mt < 2; ++mt) {
        int j0 = (jt0 + i) * 16 + quad * 4;
        int m  = mt * 16 + ln;
        store_bf4(&hs1[m * LDH + j0], acc1[i][mt]);
        store_bf4(&hs2[m * LDH + j0], acc2[i][mt]);
      }
    }
    __syncthreads();  // SYNC3: new hs1/hs2 ready

    // ======== S3: out1 (waves 0-3) / out2 (waves 4-7), N=64, K=256 ========
    {
      const ushort_t* hsrc = isOut2 ? hs2 : hs1;
      const int wbase = isOut2 ? OW2O : OW1O;
      f4v aO[2];
      aO[0] = bo3v; aO[1] = bo3v;
#pragma unroll
      for (int kk = 0; kk < 256; kk += 32) {
        bf8v b0 = *(const bf8v*)&hsrc[ln * LDH + kk + koff];
        bf8v b1 = *(const bf8v*)&hsrc[(16 + ln) * LDH + kk + koff];
        bf8v a  = *(const bf8v*)&ws[wbase + (jto3 * 16 + ln) * 256 + kk + koff];
        aO[0] = MFMA(a, b0, aO[0]);
        aO[1] = MFMA(a, b1, aO[1]);
      }
#pragma unroll
      for (int mt = 0; mt < 2; ++mt) {
#pragma unroll
        for (int r = 0; r < 4; ++r) aO[mt][r] = fast_tanh(aO[mt][r]);
        int m = mt * 16 + ln;
        size_t ob = ((size_t)t * B_TOT + m0 + m) * 64 + j0o3;
        *(f4v*)(out + (isOut2 ? O_O2 : O_O1) + ob) = aO[mt];
        store_bf4(&mid[m * LDMID + (isOut2 ? 64 : 0) + j0o3], aO[mt]);
      }
    }
    __syncthreads();  // SYNC4: mid ready

    // ======== S4: acc3 += W3i_perm x mid (K=160); tanh; write hs3 ========
#pragma unroll
    for (int kk = 0; kk < 160; kk += 32) {
      bf8v b0 = *(const bf8v*)&mid[ln * LDMID + kk + koff];
      bf8v b1 = *(const bf8v*)&mid[(16 + ln) * LDMID + kk + koff];
#pragma unroll
      for (int i = 0; i < 2; ++i) {
        bf8v a = *(const bf8v*)&ws[OW3I + ((jt0 + i) * 16 + ln) * 160 + kk + koff];
        acc3[i][0] = MFMA(a, b0, acc3[i][0]);
        acc3[i][1] = MFMA(a, b1, acc3[i][1]);
      }
    }
#pragma unroll
    for (int i = 0; i < 2; ++i) {
#pragma unroll
      for (int mt = 0; mt < 2; ++mt) {
#pragma unroll
        for (int r = 0; r < 4; ++r) acc3[i][mt][r] = fast_tanh(acc3[i][mt][r]);
        int j0 = (jt0 + i) * 16 + quad * 4;
        int m  = mt * 16 + ln;
        if (t == T_STEPS - 1)
          *(f4v*)(out + O_H3 + (size_t)(m0 + m) * 256 + j0) = acc3[i][mt];
        store_bf4(&hs3[m * LDH + j0], acc3[i][mt]);  // old hs3 readers finished at S1 (SYNC2+)
      }
    }
    __syncthreads();  // SYNC5: new hs3 ready

    // ======== S5: o = h3n @ W3o.T + b3o (N=64); -> h4s, ofa, ofs, (h4 final) ========
    {
      f4v aO = b3ov;
#pragma unroll
      for (int kk = 0; kk < 256; kk += 32) {
        bf8v b = *(const bf8v*)&hs3[mo5 * LDH + kk + koff];
        bf8v a = *(const bf8v*)&ws[OW3O + (jto5 * 16 + ln) * 256 + kk + koff];
        aO = MFMA(a, b, aO);
      }
      store_bf4(&h4s[mo5 * LDS_SM + j0o5], aO);  // h4s readers (S0) finished long ago
      if (t == T_STEPS - 1)
        *(f4v*)(out + O_H4 + (size_t)(m0 + mo5) * 64 + j0o5) = aO;
      f4v rl;
#pragma unroll
      for (int r = 0; r < 4; ++r) rl[r] = fmaxf(aO[r], 0.0f);
      *(f4v*)(out + O_OFA + ((size_t)t * B_TOT + m0 + mo5) * 64 + j0o5) = rl;
      store_bf4(&ofs[mo5 * LDS_SM + j0o5], rl);
    }
    __syncthreads();  // SYNC6: ofs/h4s ready

    // ======== S6: outf = relu(o) @ Wfc.T + bfc -> oseq (waves 0,1 only) ========
    if (w < 2) {
      f4v aFc;
      aFc[0] = (quad == 0) ? bfcv0 : 0.0f;
      aFc[1] = (quad == 0) ? bfcv1 : 0.0f;
      aFc[2] = 0.0f; aFc[3] = 0.0f;
#pragma unroll
      for (int kk = 0; kk < 64; kk += 32) {
        bf8v b = *(const bf8v*)&ofs[(w * 16 + ln) * LDS_SM + kk + koff];
        bf8v a = *(const bf8v*)&ws[OWFC + ln * 64 + kk + koff];
        aFc = MFMA(a, b, aFc);
      }
      if (quad == 0) {
        float* po = out + O_OSEQ + ((size_t)t * B_TOT + m0 + w * 16 + ln) * 2;
        po[0] = aFc[0];
        po[1] = aFc[1];
      }
    }
    // no barrier needed: next S0 writes xs (last read S1, covered by SYNC2+)
    // and reads h4s (written S5, covered by SYNC6)
  }
}

extern "C" void kernel_launch(void* const* d_in, const int* in_sizes, int n_in,
                              void* d_out, int out_size, void* d_ws, size_t ws_size,
                              hipStream_t stream) {
  const float* x   = (const float*)d_in[0];
  const float* cue = (const float*)d_in[1];
  const float* hc1 = (const float*)d_in[2];
  const float* hc2 = (const float*)d_in[3];
  const float* hc3 = (const float*)d_in[4];
  const float* hc4 = (const float*)d_in[5];
  const float* W1i = (const float*)d_in[6];
  const float* b1i = (const float*)d_in[7];
  const float* W1h = (const float*)d_in[8];
  const float* b1h = (const float*)d_in[9];
  const float* Wf1 = (const float*)d_in[10];
  const float* bf1 = (const float*)d_in[11];
  const float* W1o = (const float*)d_in[12];
  const float* b1o = (const float*)d_in[13];
  const float* W2i = (const float*)d_in[14];
  const float* b2i = (const float*)d_in[15];
  const float* W2h = (const float*)d_in[16];
  const float* b2h = (const float*)d_in[17];
  const float* Wf2 = (const float*)d_in[18];
  const float* bf2 = (const float*)d_in[19];
  const float* W2o = (const float*)d_in[20];
  const float* b2o = (const float*)d_in[21];
  const float* W3i = (const float*)d_in[22];
  const float* b3i = (const float*)d_in[23];
  const float* W3h = (const float*)d_in[24];
  const float* b3h = (const float*)d_in[25];
  const float* W3o = (const float*)d_in[26];
  const float* b3o = (const float*)d_in[27];
  const float* Wfc = (const float*)d_in[28];
  const float* bfc = (const float*)d_in[29];

  ushort_t* ws = (ushort_t*)d_ws;
  float* out = (float*)d_out;

  prep_kernel<<<(WS_TOTAL + 511) / 512, 512, 0, stream>>>(
      W1i, W1h, Wf1, W1o, W2i, W2h, Wf2, W2o, W3i, W3h, W3o, Wfc, ws);

  rnn_kernel<<<B_TOT / M_TILE, 512, 0, stream>>>(
      x, cue, hc1, hc2, hc3, hc4,
      b1i, b1h, bf1, b1o, b2i, b2h, bf2, b2o, b3i, b3h, b3o, bfc,
      ws, out);
}